// Round 1
// baseline (750.547 us; speedup 1.0000x reference)
//
#include <hip/hip_runtime.h>
#include <hip/hip_bf16.h>

#define B_    128
#define S_    1024
#define DIN   64
#define DH    256
#define DLAT  256
#define DOUT  128
#define NPIECES 20
#define ST    32      // positions per phi tile

// ---------- bf16 helpers (used only for the low-ws fallback feat path) ----------
__device__ __forceinline__ unsigned short f2b(float f) {
    union { float f; unsigned u; } a; a.f = f;
    unsigned r = a.u + 0x7fffu + ((a.u >> 16) & 1u);   // RNE
    return (unsigned short)(r >> 16);
}
__device__ __forceinline__ float b2f(unsigned short u) {
    union { unsigned u; float f; } a; a.u = ((unsigned)u) << 16;
    return a.f;
}

template <typename T> struct FeatIO;
template <> struct FeatIO<float> {
    static __device__ __forceinline__ void store4(float* p, const float* v) {
        float4 t; t.x = v[0]; t.y = v[1]; t.z = v[2]; t.w = v[3];
        *(float4*)p = t;
    }
    static __device__ __forceinline__ float load(const float* p) { return *p; }
};
template <> struct FeatIO<unsigned short> {
    static __device__ __forceinline__ void store4(unsigned short* p, const float* v) {
        ushort4 t; t.x = f2b(v[0]); t.y = f2b(v[1]); t.z = f2b(v[2]); t.w = f2b(v[3]);
        *(ushort4*)p = t;
    }
    static __device__ __forceinline__ float load(const unsigned short* p) { return b2f(*p); }
};

// ---------------- kernel 1: n per batch ----------------
__global__ __launch_bounds__(256) void k_count(const int* __restrict__ mask,
                                               int* __restrict__ nv) {
    int b = blockIdx.x, t = threadIdx.x;
    int sum = 0;
    #pragma unroll
    for (int q = 0; q < S_ / 256; ++q) sum += mask[b * S_ + q * 256 + t];
    #pragma unroll
    for (int off = 32; off > 0; off >>= 1) sum += __shfl_down(sum, off, 64);
    __shared__ int parts[4];
    if ((t & 63) == 0) parts[t >> 6] = sum;
    __syncthreads();
    if (t == 0) {
        int n = parts[0] + parts[1] + parts[2] + parts[3];
        nv[b] = max(n, 2);   // nv = max(n-1,1)+1 valid positions
    }
}

// ---------------- kernel 2: fused phi MLP, writes feat^T [B][C][S] ----------------
template <typename T>
__global__ __launch_bounds__(256) void k_phi(const float* __restrict__ x,
                                             const float* __restrict__ w1,
                                             const float* __restrict__ b1,
                                             const float* __restrict__ w2,
                                             const float* __restrict__ b2,
                                             const int* __restrict__ nv,
                                             T* __restrict__ feat) {
    const int b  = blockIdx.y;
    const int s0 = blockIdx.x * ST;
    if (s0 >= nv[b]) return;               // positions >= nv never contribute
    const int tid  = threadIdx.x;
    const int tcol = tid & 7;              // s = tcol*4 + i
    const int trow = tid >> 3;             // c = trow + 32*r

    __shared__ float xs[ST][DIN + 1];      // [s][k], col reads stride 65 -> conflict-free
    __shared__ float wch[16][DH];          // 16-k weight chunk (w1 then w2)
    __shared__ float hs[DH][ST + 1];       // h tile [k][s]

    // stage x tile [32][64]: 8 consecutive floats per thread
    {
        const float* xp = x + ((size_t)b * S_ + s0) * DIN;
        int lin = tid * 8, row = lin >> 6, col = lin & 63;
        float4 v0 = *(const float4*)(xp + row * DIN + col);
        float4 v1 = *(const float4*)(xp + row * DIN + col + 4);
        xs[row][col + 0] = v0.x; xs[row][col + 1] = v0.y;
        xs[row][col + 2] = v0.z; xs[row][col + 3] = v0.w;
        xs[row][col + 4] = v1.x; xs[row][col + 5] = v1.y;
        xs[row][col + 6] = v1.z; xs[row][col + 7] = v1.w;
    }

    float acc[8][4];
    #pragma unroll
    for (int r = 0; r < 8; ++r) {
        float bb = b1[trow + 32 * r];
        #pragma unroll
        for (int i = 0; i < 4; ++i) acc[r][i] = bb;
    }

    // ---- layer 1: h[c][s] = relu(sum_k w1[k][c] * x[s][k] + b1[c]) ----
    for (int kc = 0; kc < DIN / 16; ++kc) {
        __syncthreads();
        const float* wp = w1 + (size_t)kc * 16 * DH;
        #pragma unroll
        for (int q = 0; q < 4; ++q) {
            int lin = q * 1024 + tid * 4;
            *(float4*)&wch[lin >> 8][lin & 255] = *(const float4*)(wp + lin);
        }
        __syncthreads();
        #pragma unroll
        for (int kk = 0; kk < 16; ++kk) {
            int k = kc * 16 + kk;
            float xv[4];
            #pragma unroll
            for (int i = 0; i < 4; ++i) xv[i] = xs[tcol * 4 + i][k];
            #pragma unroll
            for (int r = 0; r < 8; ++r) {
                float wv = wch[kk][trow + 32 * r];
                #pragma unroll
                for (int i = 0; i < 4; ++i) acc[r][i] = fmaf(wv, xv[i], acc[r][i]);
            }
        }
    }
    // relu -> hs
    #pragma unroll
    for (int r = 0; r < 8; ++r) {
        int c = trow + 32 * r;
        #pragma unroll
        for (int i = 0; i < 4; ++i) hs[c][tcol * 4 + i] = fmaxf(acc[r][i], 0.f);
    }

    float fac[8][4];
    #pragma unroll
    for (int r = 0; r < 8; ++r) {
        float bb = b2[trow + 32 * r];
        #pragma unroll
        for (int i = 0; i < 4; ++i) fac[r][i] = bb;
    }

    // ---- layer 2: feat[c][s] = sum_k w2[k][c] * h[k][s] + b2[c] ----
    for (int kc = 0; kc < DH / 16; ++kc) {
        __syncthreads();   // protects hs visibility (first iter) and wch overwrite
        const float* wp = w2 + (size_t)kc * 16 * DLAT;
        #pragma unroll
        for (int q = 0; q < 4; ++q) {
            int lin = q * 1024 + tid * 4;
            *(float4*)&wch[lin >> 8][lin & 255] = *(const float4*)(wp + lin);
        }
        __syncthreads();
        #pragma unroll
        for (int kk = 0; kk < 16; ++kk) {
            int k = kc * 16 + kk;
            float hv[4];
            #pragma unroll
            for (int i = 0; i < 4; ++i) hv[i] = hs[k][tcol * 4 + i];
            #pragma unroll
            for (int r = 0; r < 8; ++r) {
                float wv = wch[kk][trow + 32 * r];
                #pragma unroll
                for (int i = 0; i < 4; ++i) fac[r][i] = fmaf(wv, hv[i], fac[r][i]);
            }
        }
    }

    // write feat^T: [b][c][s0 + tcol*4 .. +3]
    #pragma unroll
    for (int r = 0; r < 8; ++r) {
        int c = trow + 32 * r;
        FeatIO<T>::store4(feat + ((size_t)b * DLAT + c) * S_ + s0 + tcol * 4, fac[r]);
    }
}

// ---------------- kernel 3: FSPool — bitonic sort + piecewise-linear weighted sum ----------------
template <typename T>
__global__ __launch_bounds__(256) void k_fspool(const T* __restrict__ feat,
                                                const int* __restrict__ nv,
                                                const float* __restrict__ pool_w,
                                                float* __restrict__ pooled) {
    const int c = blockIdx.x, b = blockIdx.y, t = threadIdx.x;
    const int n = nv[b];
    __shared__ float v[S_];
    __shared__ float parts[4];

    const T* fp = feat + ((size_t)b * DLAT + c) * S_;
    #pragma unroll
    for (int q = 0; q < 4; ++q) {
        int j = q * 256 + t;
        v[j] = (j < n) ? FeatIO<T>::load(fp + j) : -3.0e38f;
    }
    __syncthreads();

    // bitonic sort, descending
    for (int k = 2; k <= S_; k <<= 1) {
        for (int j = k >> 1; j > 0; j >>= 1) {
            #pragma unroll
            for (int q = 0; q < 2; ++q) {
                int e = q * 256 + t;                       // 0..511 compare-exchange id
                int i = ((e & ~(j - 1)) << 1) | (e & (j - 1));
                int p = i | j;
                bool up = (i & k) == 0;                    // flipped -> overall descending
                float a = v[i], bb = v[p];
                bool sw = up ? (a < bb) : (a > bb);
                if (sw) { v[i] = bb; v[p] = a; }
            }
            __syncthreads();
        }
    }

    // weighted sum over sorted top-n
    const float denom = (float)(n - 1);                    // n >= 2 -> equals max(n-1,1)
    const float* pw = pool_w + c * (NPIECES + 1);
    float acc = 0.f;
    #pragma unroll
    for (int q = 0; q < 4; ++q) {
        int j = q * 256 + t;
        if (j < n) {
            float ratio = fminf((float)j / denom, 1.0f);
            float pos = (float)NPIECES * ratio;
            int idx = (int)floorf(pos);
            float frac = pos - (float)idx;
            float left = pw[idx];
            float right = pw[min(idx + 1, NPIECES)];
            float w = (1.0f - frac) * left + frac * right;
            acc = fmaf(v[j], w, acc);
        }
    }
    #pragma unroll
    for (int off = 32; off > 0; off >>= 1) acc += __shfl_down(acc, off, 64);
    if ((t & 63) == 0) parts[t >> 6] = acc;
    __syncthreads();
    if (t == 0) pooled[b * DLAT + c] = parts[0] + parts[1] + parts[2] + parts[3];
}

// ---------------- kernel 4: rho MLP ----------------
__global__ __launch_bounds__(256) void k_rho(const float* __restrict__ pooled,
                                             const float* __restrict__ w1,
                                             const float* __restrict__ b1,
                                             const float* __restrict__ w2,
                                             const float* __restrict__ b2,
                                             float* __restrict__ out) {
    const int b = blockIdx.x, t = threadIdx.x;
    __shared__ float pl[DLAT];
    __shared__ float h2[DH];
    pl[t] = pooled[b * DLAT + t];
    __syncthreads();
    float acc = b1[t];
    for (int k = 0; k < DLAT; ++k) acc = fmaf(pl[k], w1[k * DH + t], acc);
    h2[t] = fmaxf(acc, 0.f);
    __syncthreads();
    if (t < DOUT) {
        float o = b2[t];
        for (int k = 0; k < DH; ++k) o = fmaf(h2[k], w2[k * DOUT + t], o);
        out[b * DOUT + t] = o;
    }
}

extern "C" void kernel_launch(void* const* d_in, const int* in_sizes, int n_in,
                              void* d_out, int out_size, void* d_ws, size_t ws_size,
                              hipStream_t stream) {
    const float* x     = (const float*)d_in[0];
    const int*   mask  = (const int*)d_in[1];
    const float* pw1   = (const float*)d_in[2];
    const float* pb1   = (const float*)d_in[3];
    const float* pw2   = (const float*)d_in[4];
    const float* pb2   = (const float*)d_in[5];
    const float* rw1   = (const float*)d_in[6];
    const float* rb1   = (const float*)d_in[7];
    const float* rw2   = (const float*)d_in[8];
    const float* rb2   = (const float*)d_in[9];
    const float* poolw = (const float*)d_in[10];
    float* out = (float*)d_out;

    char* ws = (char*)d_ws;
    int* nv = (int*)ws;                                  // 128 ints @ 0
    const size_t featOff = 1024;
    const size_t nFeat   = (size_t)B_ * DLAT * S_;       // 33.5M elements
    const size_t needF32 = featOff + nFeat * 4 + (size_t)B_ * DLAT * 4;
    const bool useF32 = (ws_size >= needF32);

    k_count<<<B_, 256, 0, stream>>>(mask, nv);

    if (useF32) {
        float* feat   = (float*)(ws + featOff);
        float* pooled = (float*)(ws + featOff + nFeat * 4);
        k_phi<float><<<dim3(S_ / ST, B_), 256, 0, stream>>>(x, pw1, pb1, pw2, pb2, nv, feat);
        k_fspool<float><<<dim3(DLAT, B_), 256, 0, stream>>>(feat, nv, poolw, pooled);
        k_rho<<<B_, 256, 0, stream>>>(pooled, rw1, rb1, rw2, rb2, out);
    } else {
        unsigned short* feat = (unsigned short*)(ws + featOff);
        float* pooled = (float*)(ws + featOff + nFeat * 2);
        k_phi<unsigned short><<<dim3(S_ / ST, B_), 256, 0, stream>>>(x, pw1, pb1, pw2, pb2, nv, feat);
        k_fspool<unsigned short><<<dim3(DLAT, B_), 256, 0, stream>>>(feat, nv, poolw, pooled);
        k_rho<<<B_, 256, 0, stream>>>(pooled, rw1, rb1, rw2, rb2, out);
    }
}

// Round 2
// 217.217 us; speedup vs baseline: 3.4553x; 3.4553x over previous
//
#include <hip/hip_runtime.h>
#include <hip/hip_bf16.h>

#define B_    128
#define S_    1024
#define DIN   64
#define DH    256
#define DLAT  256
#define DOUT  128
#define NPIECES 20

typedef short bf16x8 __attribute__((ext_vector_type(8)));
typedef float f32x4  __attribute__((ext_vector_type(4)));

// ---------- bf16 helpers ----------
__device__ __forceinline__ unsigned short f2b(float f) {
    union { float f; unsigned u; } a; a.f = f;
    unsigned r = a.u + 0x7fffu + ((a.u >> 16) & 1u);   // RNE
    return (unsigned short)(r >> 16);
}
__device__ __forceinline__ float b2f(unsigned short u) {
    union { unsigned u; float f; } a; a.u = ((unsigned)u) << 16;
    return a.f;
}

// ---------------- kernel 1: n per batch ----------------
__global__ __launch_bounds__(256) void k_count(const int* __restrict__ mask,
                                               int* __restrict__ nv) {
    int b = blockIdx.x, t = threadIdx.x;
    int sum = 0;
    #pragma unroll
    for (int q = 0; q < S_ / 256; ++q) sum += mask[b * S_ + q * 256 + t];
    #pragma unroll
    for (int off = 32; off > 0; off >>= 1) sum += __shfl_down(sum, off, 64);
    __shared__ int parts[4];
    if ((t & 63) == 0) parts[t >> 6] = sum;
    __syncthreads();
    if (t == 0) {
        int n = parts[0] + parts[1] + parts[2] + parts[3];
        nv[b] = max(n, 2);   // = number of valid positions AND denom+1
    }
}

// ---------------- pack x -> bf16 A-fragment layout ----------------
// xpk[(((b*64 + st16)*2 + ks)*64 + lane)*8 + j] = bf16(x[b][st16*16 + (lane&15)][ks*32 + (lane>>4)*8 + j])
__global__ __launch_bounds__(256) void k_pack_x(const float* __restrict__ x,
                                                short* __restrict__ xpk) {
    int c = blockIdx.x * 256 + threadIdx.x;           // chunk id, 1048576 total
    int l  = c & 63;
    int ks = (c >> 6) & 1;
    int st = (c >> 7) & 63;
    int b  = c >> 13;
    int s  = st * 16 + (l & 15);
    int k0 = ks * 32 + (l >> 4) * 8;
    const float* src = x + ((size_t)(b * S_ + s)) * DIN + k0;
    float4 v0 = *(const float4*)src;
    float4 v1 = *(const float4*)(src + 4);
    bf16x8 o;
    o[0] = (short)f2b(v0.x); o[1] = (short)f2b(v0.y); o[2] = (short)f2b(v0.z); o[3] = (short)f2b(v0.w);
    o[4] = (short)f2b(v1.x); o[5] = (short)f2b(v1.y); o[6] = (short)f2b(v1.z); o[7] = (short)f2b(v1.w);
    *(bf16x8*)(xpk + (size_t)c * 8) = o;
}

// ---------------- pack weights [K][N] f32 -> bf16 B-fragment layout ----------------
// dst[((nt*KT + ks)*64 + lane)*8 + j] = bf16(src[(ks*32 + (lane>>4)*8 + j)*N + nt*16 + (lane&15)])
__global__ __launch_bounds__(256) void k_pack_w(const float* __restrict__ src,
                                                short* __restrict__ dst,
                                                int KT, int N, int nchunk) {
    int c = blockIdx.x * 256 + threadIdx.x;
    if (c >= nchunk) return;
    int l  = c & 63;
    int ks = (c >> 6) % KT;
    int nt = (c >> 6) / KT;
    int col = nt * 16 + (l & 15);
    int k0  = ks * 32 + (l >> 4) * 8;
    bf16x8 o;
    #pragma unroll
    for (int j = 0; j < 8; ++j) o[j] = (short)f2b(src[(size_t)(k0 + j) * N + col]);
    *(bf16x8*)(dst + (size_t)c * 8) = o;
}

// ---------------- fused phi MLP with MFMA; writes feat^T [B][C][S] bf16 ----------------
__global__ __launch_bounds__(256) void k_phi_mfma(const short* __restrict__ xpk,
                                                  const short* __restrict__ w1pk,
                                                  const short* __restrict__ w2pk,
                                                  const float* __restrict__ b1,
                                                  const float* __restrict__ b2,
                                                  const int* __restrict__ nv,
                                                  unsigned short* __restrict__ feat) {
    const int b    = blockIdx.y;
    const int tile = blockIdx.x;          // 64-position tile
    const int s0   = tile * 64;
    if (s0 >= nv[b]) return;
    const int tid  = threadIdx.x;
    const int w    = tid >> 6;            // wave 0..3 -> chans [64w, 64w+64)
    const int lane = tid & 63;
    const int c15  = lane & 15;
    const int q    = lane >> 4;

    __shared__ __align__(16) char lds[64 * 256 * 2];   // 32 KB: h [pos][chan] then feat^T tile [chan][pos]

    // ---- layer 1: h = relu(x @ w1 + b1), M=64 K=64 N=256 ----
    f32x4 acc1[4][4];
    #pragma unroll
    for (int mt = 0; mt < 4; ++mt)
        #pragma unroll
        for (int nt = 0; nt < 4; ++nt) acc1[mt][nt] = (f32x4)0.f;

    const short* xb = xpk + (((size_t)b * 64 + tile * 4) * 2) * 64 * 8;
    bf16x8 a1[4][2], bw[4][2];
    #pragma unroll
    for (int mt = 0; mt < 4; ++mt)
        #pragma unroll
        for (int ks = 0; ks < 2; ++ks)
            a1[mt][ks] = *(const bf16x8*)(xb + ((size_t)(mt * 2 + ks) * 64 + lane) * 8);
    #pragma unroll
    for (int nt = 0; nt < 4; ++nt)
        #pragma unroll
        for (int ks = 0; ks < 2; ++ks)
            bw[nt][ks] = *(const bf16x8*)(w1pk + ((size_t)((w * 4 + nt) * 2 + ks) * 64 + lane) * 8);
    #pragma unroll
    for (int ks = 0; ks < 2; ++ks)
        #pragma unroll
        for (int mt = 0; mt < 4; ++mt)
            #pragma unroll
            for (int nt = 0; nt < 4; ++nt)
                acc1[mt][nt] = __builtin_amdgcn_mfma_f32_16x16x32_bf16(a1[mt][ks], bw[nt][ks], acc1[mt][nt], 0, 0, 0);

    // relu + bias -> LDS h[pos][chan] bf16, 512 B rows, swizzle byte ^= (pos&7)<<4
    #pragma unroll
    for (int nt = 0; nt < 4; ++nt) {
        int chan = (w * 4 + nt) * 16 + c15;
        float bias = b1[chan];
        #pragma unroll
        for (int mt = 0; mt < 4; ++mt)
            #pragma unroll
            for (int r = 0; r < 4; ++r) {
                int pos = mt * 16 + q * 4 + r;
                float hv = fmaxf(acc1[mt][nt][r] + bias, 0.f);
                int byte = pos * 512 + chan * 2;
                byte ^= (pos & 7) << 4;
                *(unsigned short*)(lds + byte) = f2b(hv);
            }
    }
    __syncthreads();

    // ---- layer 2: feat = h @ w2 + b2, M=64 K=256 N=256 ----
    f32x4 acc2[4][4];
    #pragma unroll
    for (int mt = 0; mt < 4; ++mt)
        #pragma unroll
        for (int nt = 0; nt < 4; ++nt) acc2[mt][nt] = (f32x4)0.f;

    for (int ks2 = 0; ks2 < 8; ++ks2) {
        bf16x8 af[4];
        #pragma unroll
        for (int mt = 0; mt < 4; ++mt) {
            int pos = mt * 16 + c15;
            int byte = pos * 512 + ks2 * 64 + q * 16;
            byte ^= (pos & 7) << 4;
            af[mt] = *(const bf16x8*)(lds + byte);
        }
        #pragma unroll
        for (int nt = 0; nt < 4; ++nt) {
            bf16x8 bf_ = *(const bf16x8*)(w2pk + ((size_t)((w * 4 + nt) * 8 + ks2) * 64 + lane) * 8);
            #pragma unroll
            for (int mt = 0; mt < 4; ++mt)
                acc2[mt][nt] = __builtin_amdgcn_mfma_f32_16x16x32_bf16(af[mt], bf_, acc2[mt][nt], 0, 0, 0);
        }
    }
    __syncthreads();   // all h reads done; reuse lds as feat^T tile [chan][pos] (128 B rows)

    #pragma unroll
    for (int nt = 0; nt < 4; ++nt) {
        int chan = (w * 4 + nt) * 16 + c15;
        float bias = b2[chan];
        #pragma unroll
        for (int mt = 0; mt < 4; ++mt) {
            unsigned u0 = (unsigned)f2b(acc2[mt][nt][0] + bias) | ((unsigned)f2b(acc2[mt][nt][1] + bias) << 16);
            unsigned u1 = (unsigned)f2b(acc2[mt][nt][2] + bias) | ((unsigned)f2b(acc2[mt][nt][3] + bias) << 16);
            int pos0 = mt * 16 + q * 4;
            int byte = chan * 128 + pos0 * 2;
            byte ^= (chan & 7) << 4;           // 16B-granule swizzle
            *(uint2*)(lds + byte) = uint2{u0, u1};
        }
    }
    __syncthreads();

    // coalesced store: 2048 chunks of 16 B = 256 chans x 8 chunks
    #pragma unroll
    for (int it = 0; it < 8; ++it) {
        int L = it * 256 + tid;
        int chan = L >> 3, chunk = L & 7;
        int byte = chan * 128 + chunk * 16;
        byte ^= (chan & 7) << 4;
        uint4 val = *(const uint4*)(lds + byte);
        *(uint4*)((char*)(feat + ((size_t)b * DLAT + chan) * S_ + s0) + chunk * 16) = val;
    }
}

// ---------------- FSPool: one wave per (b,c), register bitonic sort ----------------
__global__ __launch_bounds__(256) void k_fspool2(const unsigned short* __restrict__ feat,
                                                 const int* __restrict__ nv,
                                                 const float* __restrict__ pool_w,
                                                 float* __restrict__ pooled) {
    const int gw   = blockIdx.x * 4 + (threadIdx.x >> 6);   // (b*256 + c)
    const int lane = threadIdx.x & 63;
    const int b = gw >> 8, c = gw & 255;
    const int n = nv[b];

    // load 16 elements per lane, blocked: element i = lane*16 + s
    const unsigned short* fp = feat + ((size_t)b * DLAT + c) * S_ + lane * 16;
    bf16x8 r0 = *(const bf16x8*)fp;
    bf16x8 r1 = *(const bf16x8*)(fp + 8);
    float v[16];
    const int base = lane << 4;
    #pragma unroll
    for (int s = 0; s < 8; ++s)  v[s]     = (base + s     < n) ? b2f((unsigned short)r0[s]) : -3.0e38f;
    #pragma unroll
    for (int s = 0; s < 8; ++s)  v[s + 8] = (base + s + 8 < n) ? b2f((unsigned short)r1[s]) : -3.0e38f;

    // bitonic sort (descending). j>=16 -> shfl_xor(j/16); j<16 -> in-register.
    #pragma unroll
    for (int k = 2; k <= 1024; k <<= 1) {
        #pragma unroll
        for (int j = k >> 1; j >= 16; j >>= 1) {
            const int m = j >> 4;
            #pragma unroll
            for (int s = 0; s < 16; ++s) {
                float p = __shfl_xor(v[s], m, 64);
                int i = (lane << 4) + s;
                bool dir   = ((i & k) == 0);
                bool lower = ((lane & m) == 0);
                float mx = fmaxf(v[s], p), mn = fminf(v[s], p);
                v[s] = (dir == lower) ? mx : mn;
            }
        }
        #pragma unroll
        for (int j = ((k >> 1) < 8 ? (k >> 1) : 8); j >= 1; j >>= 1) {
            #pragma unroll
            for (int s = 0; s < 16; ++s) {
                if ((s & j) == 0) {
                    int i = (lane << 4) + s;
                    bool dir = ((i & k) == 0);
                    float a = v[s], bb = v[s | j];
                    float mx = fmaxf(a, bb), mn = fminf(a, bb);
                    v[s]     = dir ? mx : mn;
                    v[s | j] = dir ? mn : mx;
                }
            }
        }
    }

    // weighted sum: element at sorted index i = lane*16+s
    const float denom = (float)(n - 1);
    const float* pw = pool_w + c * (NPIECES + 1);
    float acc = 0.f;
    #pragma unroll
    for (int s = 0; s < 16; ++s) {
        int i = (lane << 4) + s;
        if (i < n) {
            float ratio = fminf((float)i / denom, 1.0f);
            float pos = (float)NPIECES * ratio;
            int idx = (int)pos;
            float frac = pos - (float)idx;
            float left = pw[idx];
            float right = pw[min(idx + 1, NPIECES)];
            acc = fmaf(v[s], (1.0f - frac) * left + frac * right, acc);
        }
    }
    #pragma unroll
    for (int off = 32; off > 0; off >>= 1) acc += __shfl_xor(acc, off, 64);
    if (lane == 0) pooled[gw] = acc;
}

// ---------------- rho MLP ----------------
__global__ __launch_bounds__(256) void k_rho(const float* __restrict__ pooled,
                                             const float* __restrict__ w1,
                                             const float* __restrict__ b1,
                                             const float* __restrict__ w2,
                                             const float* __restrict__ b2,
                                             float* __restrict__ out) {
    const int b = blockIdx.x, t = threadIdx.x;
    __shared__ float pl[DLAT];
    __shared__ float h2[DH];
    pl[t] = pooled[b * DLAT + t];
    __syncthreads();
    float acc = b1[t];
    for (int k = 0; k < DLAT; ++k) acc = fmaf(pl[k], w1[k * DH + t], acc);
    h2[t] = fmaxf(acc, 0.f);
    __syncthreads();
    if (t < DOUT) {
        float o = b2[t];
        for (int k = 0; k < DH; ++k) o = fmaf(h2[k], w2[k * DOUT + t], o);
        out[b * DOUT + t] = o;
    }
}

extern "C" void kernel_launch(void* const* d_in, const int* in_sizes, int n_in,
                              void* d_out, int out_size, void* d_ws, size_t ws_size,
                              hipStream_t stream) {
    const float* x     = (const float*)d_in[0];
    const int*   mask  = (const int*)d_in[1];
    const float* pw1   = (const float*)d_in[2];
    const float* pb1   = (const float*)d_in[3];
    const float* pw2   = (const float*)d_in[4];
    const float* pb2   = (const float*)d_in[5];
    const float* rw1   = (const float*)d_in[6];
    const float* rb1   = (const float*)d_in[7];
    const float* rw2   = (const float*)d_in[8];
    const float* rb2   = (const float*)d_in[9];
    const float* poolw = (const float*)d_in[10];
    float* out = (float*)d_out;

    char* ws = (char*)d_ws;
    size_t off = 0;
    int* nv = (int*)ws;                          off += 1024;
    short* xpk   = (short*)(ws + off);           off += (size_t)B_ * S_ * DIN * 2;     // 16.8 MB
    short* w1pk  = (short*)(ws + off);           off += (size_t)DIN * DH * 2;          // 32 KB
    short* w2pk  = (short*)(ws + off);           off += (size_t)DH * DLAT * 2;         // 128 KB
    unsigned short* feat = (unsigned short*)(ws + off); off += (size_t)B_ * DLAT * S_ * 2; // 67 MB
    float* pooled = (float*)(ws + off);

    k_count<<<B_, 256, 0, stream>>>(mask, nv);
    k_pack_x<<<(B_ * S_ * DIN / 8) / 256, 256, 0, stream>>>(x, xpk);
    k_pack_w<<<(DIN * DH / 8 + 255) / 256, 256, 0, stream>>>(pw1, w1pk, DIN / 32, DH, DIN * DH / 8);
    k_pack_w<<<(DH * DLAT / 8 + 255) / 256, 256, 0, stream>>>(pw2, w2pk, DH / 32, DLAT, DH * DLAT / 8);
    k_phi_mfma<<<dim3(S_ / 64, B_), 256, 0, stream>>>(xpk, w1pk, w2pk, pb1, pb2, nv, feat);
    k_fspool2<<<(B_ * DLAT) / 4, 256, 0, stream>>>(feat, nv, poolw, pooled);
    k_rho<<<B_, 256, 0, stream>>>(pooled, rw1, rb1, rw2, rb2, out);
}

// Round 3
// 138.987 us; speedup vs baseline: 5.4001x; 1.5629x over previous
//
#include <hip/hip_runtime.h>
#include <hip/hip_bf16.h>

#define B_    128
#define S_    1024
#define DIN   64
#define DH    256
#define DLAT  256
#define DOUT  128
#define NPIECES 20

typedef short bf16x8 __attribute__((ext_vector_type(8)));
typedef float f32x4  __attribute__((ext_vector_type(4)));
typedef unsigned short u16x2 __attribute__((ext_vector_type(2)));

// ---------- bf16 helpers ----------
__device__ __forceinline__ unsigned short f2b(float f) {
    union { float f; unsigned u; } a; a.f = f;
    unsigned r = a.u + 0x7fffu + ((a.u >> 16) & 1u);   // RNE
    return (unsigned short)(r >> 16);
}
__device__ __forceinline__ float b2f_u(unsigned u16bits) {
    union { unsigned u; float f; } a; a.u = u16bits << 16;
    return a.f;
}

// packed u16 max/min (v_pk_max_u16 / v_pk_min_u16 when available)
__device__ __forceinline__ unsigned pmaxu(unsigned a, unsigned b) {
    union { unsigned u; u16x2 v; } A, Bv, R;
    A.u = a; Bv.u = b;
    R.v = __builtin_elementwise_max(A.v, Bv.v);
    return R.u;
}
__device__ __forceinline__ unsigned pminu(unsigned a, unsigned b) {
    union { unsigned u; u16x2 v; } A, Bv, R;
    A.u = a; Bv.u = b;
    R.v = __builtin_elementwise_min(A.v, Bv.v);
    return R.u;
}

// ---------------- kernel 1: n per batch ----------------
__global__ __launch_bounds__(256) void k_count(const int* __restrict__ mask,
                                               int* __restrict__ nv) {
    int b = blockIdx.x, t = threadIdx.x;
    int sum = 0;
    #pragma unroll
    for (int q = 0; q < S_ / 256; ++q) sum += mask[b * S_ + q * 256 + t];
    #pragma unroll
    for (int off = 32; off > 0; off >>= 1) sum += __shfl_down(sum, off, 64);
    __shared__ int parts[4];
    if ((t & 63) == 0) parts[t >> 6] = sum;
    __syncthreads();
    if (t == 0) {
        int n = parts[0] + parts[1] + parts[2] + parts[3];
        nv[b] = max(n, 2);   // = number of valid positions AND denom+1
    }
}

// ---------------- pack x -> bf16 A-fragment layout ----------------
__global__ __launch_bounds__(256) void k_pack_x(const float* __restrict__ x,
                                                short* __restrict__ xpk) {
    int c = blockIdx.x * 256 + threadIdx.x;           // chunk id, 1048576 total
    int l  = c & 63;
    int ks = (c >> 6) & 1;
    int st = (c >> 7) & 63;
    int b  = c >> 13;
    int s  = st * 16 + (l & 15);
    int k0 = ks * 32 + (l >> 4) * 8;
    const float* src = x + ((size_t)(b * S_ + s)) * DIN + k0;
    float4 v0 = *(const float4*)src;
    float4 v1 = *(const float4*)(src + 4);
    bf16x8 o;
    o[0] = (short)f2b(v0.x); o[1] = (short)f2b(v0.y); o[2] = (short)f2b(v0.z); o[3] = (short)f2b(v0.w);
    o[4] = (short)f2b(v1.x); o[5] = (short)f2b(v1.y); o[6] = (short)f2b(v1.z); o[7] = (short)f2b(v1.w);
    *(bf16x8*)(xpk + (size_t)c * 8) = o;
}

// ---------------- pack weights [K][N] f32 -> bf16 B-fragment layout ----------------
__global__ __launch_bounds__(256) void k_pack_w(const float* __restrict__ src,
                                                short* __restrict__ dst,
                                                int KT, int N, int nchunk) {
    int c = blockIdx.x * 256 + threadIdx.x;
    if (c >= nchunk) return;
    int l  = c & 63;
    int ks = (c >> 6) % KT;
    int nt = (c >> 6) / KT;
    int col = nt * 16 + (l & 15);
    int k0  = ks * 32 + (l >> 4) * 8;
    bf16x8 o;
    #pragma unroll
    for (int j = 0; j < 8; ++j) o[j] = (short)f2b(src[(size_t)(k0 + j) * N + col]);
    *(bf16x8*)(dst + (size_t)c * 8) = o;
}

// ---------------- fused phi MLP with MFMA; writes feat^T [B][C][S] bf16 ----------------
__global__ __launch_bounds__(256) void k_phi_mfma(const short* __restrict__ xpk,
                                                  const short* __restrict__ w1pk,
                                                  const short* __restrict__ w2pk,
                                                  const float* __restrict__ b1,
                                                  const float* __restrict__ b2,
                                                  const int* __restrict__ nv,
                                                  unsigned short* __restrict__ feat) {
    const int b    = blockIdx.y;
    const int tile = blockIdx.x;          // 64-position tile
    const int s0   = tile * 64;
    if (s0 >= nv[b]) return;
    const int tid  = threadIdx.x;
    const int w    = tid >> 6;            // wave 0..3 -> chans [64w, 64w+64)
    const int lane = tid & 63;
    const int c15  = lane & 15;
    const int q    = lane >> 4;

    __shared__ __align__(16) char lds[64 * 256 * 2];   // 32 KB

    // ---- layer 1: h = relu(x @ w1 + b1), M=64 K=64 N=256 ----
    f32x4 acc1[4][4];
    #pragma unroll
    for (int mt = 0; mt < 4; ++mt)
        #pragma unroll
        for (int nt = 0; nt < 4; ++nt) acc1[mt][nt] = (f32x4)0.f;

    const short* xb = xpk + (((size_t)b * 64 + tile * 4) * 2) * 64 * 8;
    bf16x8 a1[4][2], bw[4][2];
    #pragma unroll
    for (int mt = 0; mt < 4; ++mt)
        #pragma unroll
        for (int ks = 0; ks < 2; ++ks)
            a1[mt][ks] = *(const bf16x8*)(xb + ((size_t)(mt * 2 + ks) * 64 + lane) * 8);
    #pragma unroll
    for (int nt = 0; nt < 4; ++nt)
        #pragma unroll
        for (int ks = 0; ks < 2; ++ks)
            bw[nt][ks] = *(const bf16x8*)(w1pk + ((size_t)((w * 4 + nt) * 2 + ks) * 64 + lane) * 8);
    #pragma unroll
    for (int ks = 0; ks < 2; ++ks)
        #pragma unroll
        for (int mt = 0; mt < 4; ++mt)
            #pragma unroll
            for (int nt = 0; nt < 4; ++nt)
                acc1[mt][nt] = __builtin_amdgcn_mfma_f32_16x16x32_bf16(a1[mt][ks], bw[nt][ks], acc1[mt][nt], 0, 0, 0);

    // relu + bias -> LDS h[pos][chan] bf16, swizzle byte ^= (pos&7)<<4
    #pragma unroll
    for (int nt = 0; nt < 4; ++nt) {
        int chan = (w * 4 + nt) * 16 + c15;
        float bias = b1[chan];
        #pragma unroll
        for (int mt = 0; mt < 4; ++mt)
            #pragma unroll
            for (int r = 0; r < 4; ++r) {
                int pos = mt * 16 + q * 4 + r;
                float hv = fmaxf(acc1[mt][nt][r] + bias, 0.f);
                int byte = pos * 512 + chan * 2;
                byte ^= (pos & 7) << 4;
                *(unsigned short*)(lds + byte) = f2b(hv);
            }
    }
    __syncthreads();

    // ---- layer 2: feat = h @ w2 + b2, M=64 K=256 N=256 ----
    f32x4 acc2[4][4];
    #pragma unroll
    for (int mt = 0; mt < 4; ++mt)
        #pragma unroll
        for (int nt = 0; nt < 4; ++nt) acc2[mt][nt] = (f32x4)0.f;

    for (int ks2 = 0; ks2 < 8; ++ks2) {
        bf16x8 af[4];
        #pragma unroll
        for (int mt = 0; mt < 4; ++mt) {
            int pos = mt * 16 + c15;
            int byte = pos * 512 + ks2 * 64 + q * 16;
            byte ^= (pos & 7) << 4;
            af[mt] = *(const bf16x8*)(lds + byte);
        }
        #pragma unroll
        for (int nt = 0; nt < 4; ++nt) {
            bf16x8 bf_ = *(const bf16x8*)(w2pk + ((size_t)((w * 4 + nt) * 8 + ks2) * 64 + lane) * 8);
            #pragma unroll
            for (int mt = 0; mt < 4; ++mt)
                acc2[mt][nt] = __builtin_amdgcn_mfma_f32_16x16x32_bf16(af[mt], bf_, acc2[mt][nt], 0, 0, 0);
        }
    }
    __syncthreads();   // reuse lds as feat^T tile [chan][pos]

    #pragma unroll
    for (int nt = 0; nt < 4; ++nt) {
        int chan = (w * 4 + nt) * 16 + c15;
        float bias = b2[chan];
        #pragma unroll
        for (int mt = 0; mt < 4; ++mt) {
            unsigned u0 = (unsigned)f2b(acc2[mt][nt][0] + bias) | ((unsigned)f2b(acc2[mt][nt][1] + bias) << 16);
            unsigned u1 = (unsigned)f2b(acc2[mt][nt][2] + bias) | ((unsigned)f2b(acc2[mt][nt][3] + bias) << 16);
            int pos0 = mt * 16 + q * 4;
            int byte = chan * 128 + pos0 * 2;
            byte ^= (chan & 7) << 4;
            *(uint2*)(lds + byte) = uint2{u0, u1};
        }
    }
    __syncthreads();

    #pragma unroll
    for (int it = 0; it < 8; ++it) {
        int L = it * 256 + tid;
        int chan = L >> 3, chunk = L & 7;
        int byte = chan * 128 + chunk * 16;
        byte ^= (chan & 7) << 4;
        uint4 val = *(const uint4*)(lds + byte);
        *(uint4*)((char*)(feat + ((size_t)b * DLAT + chan) * S_ + s0) + chunk * 16) = val;
    }
}

// ---------------- FSPool: packed-u16 register bitonic, one wave per (b,c) ----------------
template <int EPL, bool FASTW>
__device__ __forceinline__ float fsp_sum(const unsigned short* __restrict__ fp,
                                         int n, const float* __restrict__ pw, int lane) {
    constexpr int NREG = EPL / 2;
    constexpr int N = EPL * 64;
    const int base = lane * EPL;

    unsigned r[NREG];
    {   // vector loads: EPL*2 bytes contiguous per lane
        const uint4* q = (const uint4*)(fp + base);
        uint4 a = q[0];
        r[0] = a.x; r[1] = a.y; r[2] = a.z; r[3] = a.w;
        if (EPL == 16) {
            uint4 bq = q[1];
            r[4] = bq.x; r[5] = bq.y; r[6] = bq.z; r[7] = bq.w;
        }
    }

    // bf16 -> monotone u16 key (packed): neg ? ~u : u|0x8000 ; then mask invalid to 0
    #pragma unroll
    for (int t = 0; t < NREG; ++t) {
        unsigned u = r[t];
        unsigned sgn = (u >> 15) & 0x00010001u;
        unsigned key = u ^ ((sgn * 0x7FFFu) | 0x80008000u);
        int i0 = base + 2 * t;
        unsigned keep = (i0 + 1 < n) ? 0xFFFFFFFFu : ((i0 < n) ? 0x0000FFFFu : 0u);
        r[t] = key & keep;
    }

    // bitonic sort, descending (keys: all real > 0, masked = 0 sink to bottom)
    #pragma unroll
    for (int k = 2; k <= N; k <<= 1) {
        #pragma unroll
        for (int j = k >> 1; j > 0; j >>= 1) {
            if (j >= EPL) {
                const int m = j / EPL;
                const bool dz  = (((lane * EPL) & k) == 0);
                const bool sel = (dz == ((lane & m) == 0));
                #pragma unroll
                for (int t = 0; t < NREG; ++t) {
                    unsigned p = __shfl_xor(r[t], m, 64);
                    unsigned mx = pmaxu(r[t], p), mn = pminu(r[t], p);
                    r[t] = sel ? mx : mn;
                }
            } else if (j >= 2) {
                const int jr = j >> 1;
                #pragma unroll
                for (int t = 0; t < NREG; ++t) {
                    if ((t & jr) == 0) {
                        const int tb = t | jr;
                        unsigned mx = pmaxu(r[t], r[tb]), mn = pminu(r[t], r[tb]);
                        const bool dz = ((((lane * EPL) | (2 * t)) & k) == 0);
                        r[t]  = dz ? mx : mn;
                        r[tb] = dz ? mn : mx;
                    }
                }
            } else {
                #pragma unroll
                for (int t = 0; t < NREG; ++t) {
                    unsigned sw = (r[t] >> 16) | (r[t] << 16);      // v_alignbit
                    unsigned mx = pmaxu(r[t], sw), mn = pminu(r[t], sw);
                    const bool dz = ((((lane * EPL) | (2 * t)) & k) == 0);
                    unsigned de = (mx & 0x0000FFFFu) | (mn & 0xFFFF0000u);
                    unsigned as = (mn & 0x0000FFFFu) | (mx & 0xFFFF0000u);
                    r[t] = dz ? de : as;
                }
            }
        }
    }

    // weighted sum: element at global rank i = base + s
    const float invd = 1.0f / (float)(n - 1);
    float acc = 0.f;

    float k0, k1, k2; int ib = 0;
    if (FASTW) {
        float rb = fminf((float)base * invd, 1.0f);
        ib = (int)((float)NPIECES * rb);
        if (ib > NPIECES) ib = NPIECES;
        k0 = pw[ib];
        k1 = pw[min(ib + 1, NPIECES)];
        k2 = pw[min(ib + 2, NPIECES)];
    }

    #pragma unroll
    for (int t = 0; t < NREG; ++t) {
        #pragma unroll
        for (int h = 0; h < 2; ++h) {
            int i = base + 2 * t + h;
            unsigned key = h ? (r[t] >> 16) : (r[t] & 0xFFFFu);
            unsigned tneg = ((key >> 15) & 1u) ^ 1u;
            unsigned u = key ^ (0x8000u | (tneg * 0x7FFFu));
            float v = (i < n) ? b2f_u(u) : 0.f;        // kill NaN from masked key 0
            float ratio = fminf((float)i * invd, 1.0f);
            float pos = (float)NPIECES * ratio;
            int idx = (int)pos;
            float frac = pos - (float)idx;
            float L, R;
            if (FASTW) {
                L = (idx == ib) ? k0 : k1;
                R = (idx == ib) ? k1 : k2;
            } else {
                L = pw[idx];
                R = pw[min(idx + 1, NPIECES)];
            }
            float wgt = fmaf(frac, R - L, L);
            acc = fmaf(v, wgt, acc);
        }
    }
    #pragma unroll
    for (int off = 32; off > 0; off >>= 1) acc += __shfl_xor(acc, off, 64);
    return acc;
}

__global__ __launch_bounds__(256) void k_fspool3(const unsigned short* __restrict__ feat,
                                                 const int* __restrict__ nv,
                                                 const float* __restrict__ pool_w,
                                                 float* __restrict__ pooled) {
    const int gw   = blockIdx.x * 4 + (threadIdx.x >> 6);
    const int lane = threadIdx.x & 63;
    const int b = gw >> 8, c = gw & 255;
    const int n = nv[b];
    const unsigned short* fp = feat + ((size_t)b * DLAT + c) * S_;
    const float* pw = pool_w + c * (NPIECES + 1);

    float res;
    if (n <= 512) {
        if (n >= 20 * 7 + 1) res = fsp_sum<8, true >(fp, n, pw, lane);
        else                 res = fsp_sum<8, false>(fp, n, pw, lane);
    } else {
        res = fsp_sum<16, true>(fp, n, pw, lane);     // n > 512 >= 20*15+1
    }
    if (lane == 0) pooled[gw] = res;
}

// ---------------- rho MLP ----------------
__global__ __launch_bounds__(256) void k_rho(const float* __restrict__ pooled,
                                             const float* __restrict__ w1,
                                             const float* __restrict__ b1,
                                             const float* __restrict__ w2,
                                             const float* __restrict__ b2,
                                             float* __restrict__ out) {
    const int b = blockIdx.x, t = threadIdx.x;
    __shared__ float pl[DLAT];
    __shared__ float h2[DH];
    pl[t] = pooled[b * DLAT + t];
    __syncthreads();
    float acc = b1[t];
    for (int k = 0; k < DLAT; ++k) acc = fmaf(pl[k], w1[k * DH + t], acc);
    h2[t] = fmaxf(acc, 0.f);
    __syncthreads();
    if (t < DOUT) {
        float o = b2[t];
        for (int k = 0; k < DH; ++k) o = fmaf(h2[k], w2[k * DOUT + t], o);
        out[b * DOUT + t] = o;
    }
}

extern "C" void kernel_launch(void* const* d_in, const int* in_sizes, int n_in,
                              void* d_out, int out_size, void* d_ws, size_t ws_size,
                              hipStream_t stream) {
    const float* x     = (const float*)d_in[0];
    const int*   mask  = (const int*)d_in[1];
    const float* pw1   = (const float*)d_in[2];
    const float* pb1   = (const float*)d_in[3];
    const float* pw2   = (const float*)d_in[4];
    const float* pb2   = (const float*)d_in[5];
    const float* rw1   = (const float*)d_in[6];
    const float* rb1   = (const float*)d_in[7];
    const float* rw2   = (const float*)d_in[8];
    const float* rb2   = (const float*)d_in[9];
    const float* poolw = (const float*)d_in[10];
    float* out = (float*)d_out;

    char* ws = (char*)d_ws;
    size_t off = 0;
    int* nv = (int*)ws;                          off += 1024;
    short* xpk   = (short*)(ws + off);           off += (size_t)B_ * S_ * DIN * 2;
    short* w1pk  = (short*)(ws + off);           off += (size_t)DIN * DH * 2;
    short* w2pk  = (short*)(ws + off);           off += (size_t)DH * DLAT * 2;
    unsigned short* feat = (unsigned short*)(ws + off); off += (size_t)B_ * DLAT * S_ * 2;
    float* pooled = (float*)(ws + off);

    k_count<<<B_, 256, 0, stream>>>(mask, nv);
    k_pack_x<<<(B_ * S_ * DIN / 8) / 256, 256, 0, stream>>>(x, xpk);
    k_pack_w<<<(DIN * DH / 8 + 255) / 256, 256, 0, stream>>>(pw1, w1pk, DIN / 32, DH, DIN * DH / 8);
    k_pack_w<<<(DH * DLAT / 8 + 255) / 256, 256, 0, stream>>>(pw2, w2pk, DH / 32, DLAT, DH * DLAT / 8);
    k_phi_mfma<<<dim3(S_ / 64, B_), 256, 0, stream>>>(xpk, w1pk, w2pk, pb1, pb2, nv, feat);
    k_fspool3<<<(B_ * DLAT) / 4, 256, 0, stream>>>(feat, nv, poolw, pooled);
    k_rho<<<B_, 256, 0, stream>>>(pooled, rw1, rb1, rw2, rb2, out);
}

// Round 4
// 132.781 us; speedup vs baseline: 5.6525x; 1.0467x over previous
//
#include <hip/hip_runtime.h>
#include <hip/hip_bf16.h>

#define B_    128
#define S_    1024
#define DIN   64
#define DH    256
#define DLAT  256
#define DOUT  128
#define NPIECES 20

typedef short bf16x8 __attribute__((ext_vector_type(8)));
typedef float f32x4  __attribute__((ext_vector_type(4)));
typedef unsigned short u16x2 __attribute__((ext_vector_type(2)));

// ---------- bf16 helpers ----------
__device__ __forceinline__ unsigned short f2b(float f) {
    union { float f; unsigned u; } a; a.f = f;
    unsigned r = a.u + 0x7fffu + ((a.u >> 16) & 1u);   // RNE
    return (unsigned short)(r >> 16);
}
__device__ __forceinline__ float b2f_u(unsigned u16bits) {
    union { unsigned u; float f; } a; a.u = u16bits << 16;
    return a.f;
}
__device__ __forceinline__ unsigned pmaxu(unsigned a, unsigned b) {
    union { unsigned u; u16x2 v; } A, Bv, R;
    A.u = a; Bv.u = b;
    R.v = __builtin_elementwise_max(A.v, Bv.v);
    return R.u;
}
__device__ __forceinline__ unsigned pminu(unsigned a, unsigned b) {
    union { unsigned u; u16x2 v; } A, Bv, R;
    A.u = a; Bv.u = b;
    R.v = __builtin_elementwise_min(A.v, Bv.v);
    return R.u;
}
__device__ __forceinline__ unsigned ror16(unsigned x) { return (x >> 16) | (x << 16); }

__device__ __forceinline__ bf16x8 cvt8(float4 a, float4 b) {
    bf16x8 o;
    o[0] = (short)f2b(a.x); o[1] = (short)f2b(a.y); o[2] = (short)f2b(a.z); o[3] = (short)f2b(a.w);
    o[4] = (short)f2b(b.x); o[5] = (short)f2b(b.y); o[6] = (short)f2b(b.z); o[7] = (short)f2b(b.w);
    return o;
}

// ---------------- k_prep: mask-count + weight packing, one launch ----------------
__global__ __launch_bounds__(256) void k_prep(const int* __restrict__ mask,
                                              int* __restrict__ nv,
                                              const float* __restrict__ w1,
                                              short* __restrict__ w1pk,
                                              const float* __restrict__ w2,
                                              short* __restrict__ w2pk) {
    __shared__ int parts[4];
    const int blk = blockIdx.x, t = threadIdx.x;
    if (blk < B_) {
        int sum = 0;
        #pragma unroll
        for (int q = 0; q < S_ / 256; ++q) sum += mask[blk * S_ + q * 256 + t];
        #pragma unroll
        for (int off = 32; off > 0; off >>= 1) sum += __shfl_down(sum, off, 64);
        if ((t & 63) == 0) parts[t >> 6] = sum;
        __syncthreads();
        if (t == 0) nv[blk] = max(parts[0] + parts[1] + parts[2] + parts[3], 2);
    } else if (blk < B_ + 8) {
        int c = (blk - B_) * 256 + t;            // 2048 chunks, KT=2, N=DH
        int l = c & 63, ks = (c >> 6) % 2, nt = (c >> 6) / 2;
        int col = nt * 16 + (l & 15);
        int k0 = ks * 32 + (l >> 4) * 8;
        bf16x8 o;
        #pragma unroll
        for (int j = 0; j < 8; ++j) o[j] = (short)f2b(w1[(size_t)(k0 + j) * DH + col]);
        *(bf16x8*)(w1pk + (size_t)c * 8) = o;
    } else {
        int c = (blk - B_ - 8) * 256 + t;        // 8192 chunks, KT=8, N=DLAT
        int l = c & 63, ks = (c >> 6) % 8, nt = (c >> 6) / 8;
        int col = nt * 16 + (l & 15);
        int k0 = ks * 32 + (l >> 4) * 8;
        bf16x8 o;
        #pragma unroll
        for (int j = 0; j < 8; ++j) o[j] = (short)f2b(w2[(size_t)(k0 + j) * DLAT + col]);
        *(bf16x8*)(w2pk + (size_t)c * 8) = o;
    }
}

// ---------------- fused phi MLP with MFMA; direct f32 x loads; writes feat^T bf16 ----------------
__global__ __launch_bounds__(256) void k_phi_mfma(const float* __restrict__ x,
                                                  const short* __restrict__ w1pk,
                                                  const short* __restrict__ w2pk,
                                                  const float* __restrict__ b1,
                                                  const float* __restrict__ b2,
                                                  const int* __restrict__ nv,
                                                  unsigned short* __restrict__ feat) {
    const int b    = blockIdx.y;
    const int tile = blockIdx.x;          // 64-position tile
    const int s0   = tile * 64;
    if (s0 >= nv[b]) return;
    const int tid  = threadIdx.x;
    const int w    = tid >> 6;
    const int lane = tid & 63;
    const int c15  = lane & 15;
    const int q    = lane >> 4;

    __shared__ __align__(16) char lds[64 * 256 * 2];   // 32 KB

    // ---- layer 1: h = relu(x @ w1 + b1), M=64 K=64 N=256 ----
    f32x4 acc1[4][4];
    #pragma unroll
    for (int mt = 0; mt < 4; ++mt)
        #pragma unroll
        for (int nt = 0; nt < 4; ++nt) acc1[mt][nt] = (f32x4)0.f;

    const float* xb = x + ((size_t)b * S_ + s0) * DIN;
    bf16x8 a1[4][2], bw[4][2];
    #pragma unroll
    for (int mt = 0; mt < 4; ++mt)
        #pragma unroll
        for (int ks = 0; ks < 2; ++ks) {
            const float* p = xb + (size_t)(mt * 16 + c15) * DIN + ks * 32 + q * 8;
            float4 v0 = *(const float4*)p;
            float4 v1 = *(const float4*)(p + 4);
            a1[mt][ks] = cvt8(v0, v1);
        }
    #pragma unroll
    for (int nt = 0; nt < 4; ++nt)
        #pragma unroll
        for (int ks = 0; ks < 2; ++ks)
            bw[nt][ks] = *(const bf16x8*)(w1pk + ((size_t)((w * 4 + nt) * 2 + ks) * 64 + lane) * 8);
    #pragma unroll
    for (int ks = 0; ks < 2; ++ks)
        #pragma unroll
        for (int mt = 0; mt < 4; ++mt)
            #pragma unroll
            for (int nt = 0; nt < 4; ++nt)
                acc1[mt][nt] = __builtin_amdgcn_mfma_f32_16x16x32_bf16(a1[mt][ks], bw[nt][ks], acc1[mt][nt], 0, 0, 0);

    // relu + bias -> LDS h[pos][chan] bf16, swizzle byte ^= (pos&7)<<4
    #pragma unroll
    for (int nt = 0; nt < 4; ++nt) {
        int chan = (w * 4 + nt) * 16 + c15;
        float bias = b1[chan];
        #pragma unroll
        for (int mt = 0; mt < 4; ++mt)
            #pragma unroll
            for (int r = 0; r < 4; ++r) {
                int pos = mt * 16 + q * 4 + r;
                float hv = fmaxf(acc1[mt][nt][r] + bias, 0.f);
                int byte = pos * 512 + chan * 2;
                byte ^= (pos & 7) << 4;
                *(unsigned short*)(lds + byte) = f2b(hv);
            }
    }
    __syncthreads();

    // ---- layer 2: feat = h @ w2 + b2, M=64 K=256 N=256 ----
    f32x4 acc2[4][4];
    #pragma unroll
    for (int mt = 0; mt < 4; ++mt)
        #pragma unroll
        for (int nt = 0; nt < 4; ++nt) acc2[mt][nt] = (f32x4)0.f;

    for (int ks2 = 0; ks2 < 8; ++ks2) {
        bf16x8 af[4];
        #pragma unroll
        for (int mt = 0; mt < 4; ++mt) {
            int pos = mt * 16 + c15;
            int byte = pos * 512 + ks2 * 64 + q * 16;
            byte ^= (pos & 7) << 4;
            af[mt] = *(const bf16x8*)(lds + byte);
        }
        #pragma unroll
        for (int nt = 0; nt < 4; ++nt) {
            bf16x8 bf_ = *(const bf16x8*)(w2pk + ((size_t)((w * 4 + nt) * 8 + ks2) * 64 + lane) * 8);
            #pragma unroll
            for (int mt = 0; mt < 4; ++mt)
                acc2[mt][nt] = __builtin_amdgcn_mfma_f32_16x16x32_bf16(af[mt], bf_, acc2[mt][nt], 0, 0, 0);
        }
    }
    __syncthreads();   // reuse lds as feat^T tile [chan][pos]

    #pragma unroll
    for (int nt = 0; nt < 4; ++nt) {
        int chan = (w * 4 + nt) * 16 + c15;
        float bias = b2[chan];
        #pragma unroll
        for (int mt = 0; mt < 4; ++mt) {
            unsigned u0 = (unsigned)f2b(acc2[mt][nt][0] + bias) | ((unsigned)f2b(acc2[mt][nt][1] + bias) << 16);
            unsigned u1 = (unsigned)f2b(acc2[mt][nt][2] + bias) | ((unsigned)f2b(acc2[mt][nt][3] + bias) << 16);
            int pos0 = mt * 16 + q * 4;
            int byte = chan * 128 + pos0 * 2;
            byte ^= (chan & 7) << 4;
            *(uint2*)(lds + byte) = uint2{u0, u1};
        }
    }
    __syncthreads();

    #pragma unroll
    for (int it = 0; it < 8; ++it) {
        int L = it * 256 + tid;
        int chan = L >> 3, chunk = L & 7;
        int byte = chan * 128 + chunk * 16;
        byte ^= (chan & 7) << 4;
        uint4 val = *(const uint4*)(lds + byte);
        *(uint4*)((char*)(feat + ((size_t)b * DLAT + chan) * S_ + s0) + chunk * 16) = val;
    }
}

// ================= FSPool building blocks =================

// load 8 contiguous bf16 at element index i0, convert to sortable u16 keys, mask i>=n to 0
template <int T0, int NREGS>
__device__ __forceinline__ void loadcvt4(const unsigned short* __restrict__ fp, int i0, int n,
                                         unsigned (&r)[NREGS]) {
    uint4 a = *(const uint4*)(fp + i0);
    r[T0 + 0] = a.x; r[T0 + 1] = a.y; r[T0 + 2] = a.z; r[T0 + 3] = a.w;
    #pragma unroll
    for (int t = 0; t < 4; ++t) {
        unsigned u = r[T0 + t];
        unsigned sgn = (u >> 15) & 0x00010001u;
        unsigned key = u ^ ((sgn * 0x7FFFu) | 0x80008000u);
        int e0 = i0 + 2 * t;
        unsigned keep = (e0 + 1 < n) ? 0xFFFFFFFFu : ((e0 < n) ? 0x0000FFFFu : 0u);
        r[T0 + t] = key & keep;
    }
}

// one cross-lane compare-exchange pass (j = m*8), local idx = lane*8 + slot
template <int T0, int NREGS>
__device__ __forceinline__ void pass_cross(unsigned (&r)[NREGS], int lane, int m, int k) {
    bool lower = ((lane & m) == 0);
    bool dz = (((lane << 3) & k) == 0);
    bool sel = (dz == lower);
    #pragma unroll
    for (int t = 0; t < 4; ++t) {
        unsigned p = __shfl_xor(r[T0 + t], m, 64);
        unsigned mx = pmaxu(r[T0 + t], p), mn = pminu(r[T0 + t], p);
        r[T0 + t] = sel ? mx : mn;
    }
}

template <int T0, int NREGS>
__device__ __forceinline__ void pass_pair(unsigned (&r)[NREGS], int lane, int jr, int k) {
    #pragma unroll
    for (int t = 0; t < 4; ++t)
        if ((t & jr) == 0) {
            int ta = T0 + t, tb = T0 + (t | jr);
            unsigned mx = pmaxu(r[ta], r[tb]), mn = pminu(r[ta], r[tb]);
            bool dz = ((((lane << 3) | (t << 1)) & k) == 0);
            r[ta] = dz ? mx : mn;
            r[tb] = dz ? mn : mx;
        }
}

template <int T0, int NREGS>
__device__ __forceinline__ void pass_inpack(unsigned (&r)[NREGS], int lane, int k) {
    #pragma unroll
    for (int t = 0; t < 4; ++t) {
        unsigned v = r[T0 + t];
        unsigned sw = ror16(v);
        unsigned mx = pmaxu(v, sw), mn = pminu(v, sw);
        bool dz = ((((lane << 3) | (t << 1)) & k) == 0);
        unsigned de = (mx & 0x0000FFFFu) | (mn & 0xFFFF0000u);
        unsigned as = (mn & 0x0000FFFFu) | (mx & 0xFFFF0000u);
        r[T0 + t] = dz ? de : as;
    }
}

// full bitonic sort (descending) of NET elements laid out lane*8+slot on regs r[T0..T0+3]
template <int NET, int T0, int NREGS>
__device__ __forceinline__ void sort_net(unsigned (&r)[NREGS], int lane) {
    #pragma unroll
    for (int k = 2; k <= NET; k <<= 1) {
        #pragma unroll
        for (int j = k >> 1; j > 0; j >>= 1) {
            if (j >= 8)      pass_cross<T0>(r, lane, j >> 3, k);
            else if (j >= 2) pass_pair<T0>(r, lane, j >> 1, k);
            else             pass_inpack<T0>(r, lane, k);
        }
    }
}

// merge two bitonic 512-sequences (r[0..3] and r[4..7]) each to descending
__device__ __forceinline__ void merge_desc512_dual(unsigned (&r)[8], int lane) {
    #pragma unroll
    for (int j = 256; j >= 8; j >>= 1) {
        const int m = j >> 3;
        bool sel = ((lane & m) == 0);
        #pragma unroll
        for (int t = 0; t < 8; ++t) {
            unsigned p = __shfl_xor(r[t], m, 64);
            unsigned mx = pmaxu(r[t], p), mn = pminu(r[t], p);
            r[t] = sel ? mx : mn;
        }
    }
    #pragma unroll
    for (int jr = 2; jr >= 1; jr >>= 1)
        #pragma unroll
        for (int g = 0; g < 8; g += 4)
            #pragma unroll
            for (int t = 0; t < 4; ++t)
                if ((t & jr) == 0) {
                    unsigned a = r[g + t], bb = r[g + (t | jr)];
                    r[g + t]        = pmaxu(a, bb);
                    r[g + (t | jr)] = pminu(a, bb);
                }
    #pragma unroll
    for (int t = 0; t < 8; ++t) {
        unsigned sw = ror16(r[t]);
        unsigned mx = pmaxu(r[t], sw), mn = pminu(r[t], sw);
        r[t] = (mx & 0x0000FFFFu) | (mn & 0xFFFF0000u);
    }
}

// weighted sum over 4 regs (8 sorted elements at ranks rankBase..rankBase+7)
template <bool FASTW, int T0, int NREGS>
__device__ __forceinline__ float wsum(const unsigned (&r)[NREGS], int rankBase, int n,
                                      float invd, const float* __restrict__ pw) {
    float acc = 0.f;
    float k0 = 0.f, k1 = 0.f, k2 = 0.f; int ib = 0;
    if (FASTW) {
        float rb = fminf((float)rankBase * invd, 1.0f);
        ib = (int)((float)NPIECES * rb);
        if (ib > NPIECES) ib = NPIECES;
        k0 = pw[ib]; k1 = pw[min(ib + 1, NPIECES)]; k2 = pw[min(ib + 2, NPIECES)];
    }
    #pragma unroll
    for (int t = 0; t < 4; ++t)
        #pragma unroll
        for (int h = 0; h < 2; ++h) {
            int i = rankBase + 2 * t + h;
            unsigned key = h ? (r[T0 + t] >> 16) : (r[T0 + t] & 0xFFFFu);
            unsigned tneg = ((key >> 15) & 1u) ^ 1u;
            unsigned u = key ^ (0x8000u | (tneg * 0x7FFFu));
            float v = (i < n) ? b2f_u(u) : 0.f;
            float ratio = fminf((float)i * invd, 1.0f);
            float pos = (float)NPIECES * ratio;
            int idx = (int)pos;
            float frac = pos - (float)idx;
            float L, R;
            if (FASTW) { L = (idx == ib) ? k0 : k1; R = (idx == ib) ? k1 : k2; }
            else       { L = pw[idx];  R = pw[min(idx + 1, NPIECES)]; }
            acc = fmaf(v, fmaf(frac, R - L, L), acc);
        }
    return acc;
}

// fallback: full E=16 blocked bitonic (n > 640), returns per-lane partial
__device__ __forceinline__ float fsp_sum16(const unsigned short* __restrict__ fp,
                                           int n, const float* __restrict__ pw, int lane) {
    const int base = lane * 16;
    unsigned r[8];
    {
        const uint4* q4 = (const uint4*)(fp + base);
        uint4 a = q4[0], bq = q4[1];
        r[0] = a.x;  r[1] = a.y;  r[2] = a.z;  r[3] = a.w;
        r[4] = bq.x; r[5] = bq.y; r[6] = bq.z; r[7] = bq.w;
    }
    #pragma unroll
    for (int t = 0; t < 8; ++t) {
        unsigned u = r[t];
        unsigned sgn = (u >> 15) & 0x00010001u;
        unsigned key = u ^ ((sgn * 0x7FFFu) | 0x80008000u);
        int i0 = base + 2 * t;
        unsigned keep = (i0 + 1 < n) ? 0xFFFFFFFFu : ((i0 < n) ? 0x0000FFFFu : 0u);
        r[t] = key & keep;
    }
    #pragma unroll
    for (int k = 2; k <= 1024; k <<= 1) {
        #pragma unroll
        for (int j = k >> 1; j > 0; j >>= 1) {
            if (j >= 16) {
                const int m = j >> 4;
                const bool dz  = (((lane * 16) & k) == 0);
                const bool sel = (dz == ((lane & m) == 0));
                #pragma unroll
                for (int t = 0; t < 8; ++t) {
                    unsigned p = __shfl_xor(r[t], m, 64);
                    unsigned mx = pmaxu(r[t], p), mn = pminu(r[t], p);
                    r[t] = sel ? mx : mn;
                }
            } else if (j >= 2) {
                const int jr = j >> 1;
                #pragma unroll
                for (int t = 0; t < 8; ++t)
                    if ((t & jr) == 0) {
                        const int tb = t | jr;
                        unsigned mx = pmaxu(r[t], r[tb]), mn = pminu(r[t], r[tb]);
                        const bool dz = ((((lane * 16) | (2 * t)) & k) == 0);
                        r[t]  = dz ? mx : mn;
                        r[tb] = dz ? mn : mx;
                    }
            } else {
                #pragma unroll
                for (int t = 0; t < 8; ++t) {
                    unsigned sw = ror16(r[t]);
                    unsigned mx = pmaxu(r[t], sw), mn = pminu(r[t], sw);
                    const bool dz = ((((lane * 16) | (2 * t)) & k) == 0);
                    unsigned de = (mx & 0x0000FFFFu) | (mn & 0xFFFF0000u);
                    unsigned as = (mn & 0x0000FFFFu) | (mx & 0xFFFF0000u);
                    r[t] = dz ? de : as;
                }
            }
        }
    }
    const float invd = 1.0f / (float)(n - 1);
    float acc = 0.f;
    float rb = fminf((float)base * invd, 1.0f);
    int ib = (int)((float)NPIECES * rb);
    if (ib > NPIECES) ib = NPIECES;
    float k0 = pw[ib], k1 = pw[min(ib + 1, NPIECES)], k2 = pw[min(ib + 2, NPIECES)];
    #pragma unroll
    for (int t = 0; t < 8; ++t)
        #pragma unroll
        for (int h = 0; h < 2; ++h) {
            int i = base + 2 * t + h;
            unsigned key = h ? (r[t] >> 16) : (r[t] & 0xFFFFu);
            unsigned tneg = ((key >> 15) & 1u) ^ 1u;
            unsigned u = key ^ (0x8000u | (tneg * 0x7FFFu));
            float v = (i < n) ? b2f_u(u) : 0.f;
            float ratio = fminf((float)i * invd, 1.0f);
            float pos = (float)NPIECES * ratio;
            int idx = (int)pos;
            float frac = pos - (float)idx;
            float L = (idx == ib) ? k0 : k1, R = (idx == ib) ? k1 : k2;
            acc = fmaf(v, fmaf(frac, R - L, L), acc);
        }
    return acc;
}

// ---------------- FSPool kernel: one wave per (b,c) ----------------
__global__ __launch_bounds__(256) void k_fspool4(const unsigned short* __restrict__ feat,
                                                 const int* __restrict__ nv,
                                                 const float* __restrict__ pool_w,
                                                 float* __restrict__ pooled) {
    const int gw   = blockIdx.x * 4 + (threadIdx.x >> 6);
    const int lane = threadIdx.x & 63;
    const int b = gw >> 8, c = gw & 255;
    const int n = nv[b];
    const unsigned short* fp = feat + ((size_t)b * DLAT + c) * S_;
    const float* pw = pool_w + c * (NPIECES + 1);
    const float invd = 1.0f / (float)(n - 1);

    float res;
    if (n <= 512) {
        unsigned r[4];
        loadcvt4<0>(fp, lane * 8, n, r);
        sort_net<512, 0>(r, lane);
        res = (n >= 141) ? wsum<true, 0>(r, lane * 8, n, invd, pw)
                         : wsum<false, 0>(r, lane * 8, n, invd, pw);
    } else if (n <= 640) {
        unsigned r[8];
        loadcvt4<0>(fp, lane * 8, n, r);          // A: elements 0..511
        loadcvt4<4>(fp, 512 + lane * 8, n, r);    // B: elements 512..1023 (valid tail <=128)
        sort_net<512, 0>(r, lane);                // sort A desc
        sort_net<128, 4>(r, lane);                // sort B's 128-elem head desc (rest zero)
        // half-cleaner: A[i] vs B[511-i]  (lane^63, reg 7-t / 3-t, halves swapped)
        unsigned pa[4], pb[4];
        #pragma unroll
        for (int t = 0; t < 4; ++t) pa[t] = ror16(__shfl_xor(r[7 - t], 63, 64));
        #pragma unroll
        for (int t = 0; t < 4; ++t) pb[t] = ror16(__shfl_xor(r[3 - t], 63, 64));
        #pragma unroll
        for (int t = 0; t < 4; ++t) r[t]     = pmaxu(r[t], pa[t]);
        #pragma unroll
        for (int t = 0; t < 4; ++t) r[4 + t] = pminu(r[4 + t], pb[t]);
        merge_desc512_dual(r, lane);
        res = wsum<true, 0>(r, lane * 8, n, invd, pw)
            + wsum<true, 4>(r, 512 + lane * 8, n, invd, pw);
    } else {
        res = fsp_sum16(fp, n, pw, lane);
    }
    #pragma unroll
    for (int off = 32; off > 0; off >>= 1) res += __shfl_xor(res, off, 64);
    if (lane == 0) pooled[gw] = res;
}

// ---------------- rho MLP ----------------
__global__ __launch_bounds__(256) void k_rho(const float* __restrict__ pooled,
                                             const float* __restrict__ w1,
                                             const float* __restrict__ b1,
                                             const float* __restrict__ w2,
                                             const float* __restrict__ b2,
                                             float* __restrict__ out) {
    const int b = blockIdx.x, t = threadIdx.x;
    __shared__ float pl[DLAT];
    __shared__ float h2[DH];
    pl[t] = pooled[b * DLAT + t];
    __syncthreads();
    float acc = b1[t];
    for (int k = 0; k < DLAT; ++k) acc = fmaf(pl[k], w1[k * DH + t], acc);
    h2[t] = fmaxf(acc, 0.f);
    __syncthreads();
    if (t < DOUT) {
        float o = b2[t];
        for (int k = 0; k < DH; ++k) o = fmaf(h2[k], w2[k * DOUT + t], o);
        out[b * DOUT + t] = o;
    }
}

extern "C" void kernel_launch(void* const* d_in, const int* in_sizes, int n_in,
                              void* d_out, int out_size, void* d_ws, size_t ws_size,
                              hipStream_t stream) {
    const float* x     = (const float*)d_in[0];
    const int*   mask  = (const int*)d_in[1];
    const float* pw1   = (const float*)d_in[2];
    const float* pb1   = (const float*)d_in[3];
    const float* pw2   = (const float*)d_in[4];
    const float* pb2   = (const float*)d_in[5];
    const float* rw1   = (const float*)d_in[6];
    const float* rb1   = (const float*)d_in[7];
    const float* rw2   = (const float*)d_in[8];
    const float* rb2   = (const float*)d_in[9];
    const float* poolw = (const float*)d_in[10];
    float* out = (float*)d_out;

    char* ws = (char*)d_ws;
    size_t off = 0;
    int* nv = (int*)ws;                          off += 1024;
    short* w1pk  = (short*)(ws + off);           off += (size_t)DIN * DH * 2;
    short* w2pk  = (short*)(ws + off);           off += (size_t)DH * DLAT * 2;
    unsigned short* feat = (unsigned short*)(ws + off); off += (size_t)B_ * DLAT * S_ * 2;
    float* pooled = (float*)(ws + off);

    k_prep<<<B_ + 8 + 32, 256, 0, stream>>>(mask, nv, pw1, w1pk, pw2, w2pk);
    k_phi_mfma<<<dim3(S_ / 64, B_), 256, 0, stream>>>(x, w1pk, w2pk, pb1, pb2, nv, feat);
    k_fspool4<<<(B_ * DLAT) / 4, 256, 0, stream>>>(feat, nv, poolw, pooled);
    k_rho<<<B_, 256, 0, stream>>>(pooled, rw1, rb1, rw2, rb2, out);
}